// Round 18
// baseline (911.828 us; speedup 1.0000x reference)
//
#include <hip/hip_runtime.h>
#include <math.h>

#define T_TOKENS 100352

typedef short s16x8 __attribute__((ext_vector_type(8)));
typedef float f32x4 __attribute__((ext_vector_type(4)));

__device__ __forceinline__ unsigned short f2b(float f) {
    union { float f; unsigned u; } x; x.f = f;
    unsigned r = x.u + 0x7fffu + ((x.u >> 16) & 1u);   // RNE
    return (unsigned short)(r >> 16);
}
__device__ __forceinline__ float b2f(unsigned short h) {
    union { unsigned u; float f; } x; x.u = (unsigned)h << 16;
    return x.f;
}

#define GLOAD_LDS16(gsrc, ldst) __builtin_amdgcn_global_load_lds( \
    (const __attribute__((address_space(1))) void*)(gsrc), \
    (__attribute__((address_space(3))) void*)(ldst), 16, 0, 0)

__device__ __forceinline__ int win_row_to_token(int r, int shifted) {
    int widx = r / 98;
    int n = r - widx * 98;
    int b = widx >> 9;
    int remw = widx & 511;
    int dW = remw >> 6, hW = (remw >> 3) & 7, wW = remw & 7;
    int zd = n / 49;
    int nr = n - zd * 49;
    int zh = nr / 7, zw = nr - zh * 7;
    int d = dW * 2 + zd, h = hW * 7 + zh, w = wW * 7 + zw;
    if (shifted) {
        d = (d + 1) & 15;
        h += 3; if (h >= 56) h -= 56;
        w += 3; if (w >= 56) w -= 56;
    }
    return ((b * 16 + d) * 56 + h) * 56 + w;
}

__global__ __launch_bounds__(256) void f2b_kernel(
    const float* __restrict__ in, unsigned short* __restrict__ out, int n)
{
    int i = blockIdx.x * 256 + threadIdx.x;
    if (i < n) out[i] = f2b(in[i]);
}

// Combined bias+mask map, pre-scaled by log2(e), bf16.
__global__ __launch_bounds__(256) void bias_kernel(
    const float* __restrict__ table, unsigned short* __restrict__ bmc)
{
    int idx = blockIdx.x * 256 + threadIdx.x;
    if (idx >= 921984) return;
    int l = idx / 460992;
    int r = idx - l * 460992;
    int cls = r / 57624;
    int r2 = r - cls * 57624;
    int h = r2 / 9604;
    int e = r2 - h * 9604;
    int n = e / 98, m = e - n * 98;
    int zd = n / 49, nr = n - zd * 49, zh = nr / 7, zw = nr - zh * 7;
    int yd = m / 49, mr = m - yd * 49, yh = mr / 7, yw = mr - yh * 7;
    int rpi = (zd - yd + 1) * 169 + (zh - yh + 6) * 13 + (zw - yw + 6);
    float v = table[l * 3042 + rpi * 6 + h];
    int rn = (((cls >> 2) & 1) ? 1 + zd : 0) * 9
           + (((cls >> 1) & 1) ? (zh < 4 ? 1 : 2) : 0) * 3
           + ((cls & 1) ? (zw < 4 ? 1 : 2) : 0);
    int rm2 = (((cls >> 2) & 1) ? 1 + yd : 0) * 9
            + (((cls >> 1) & 1) ? (yh < 4 ? 1 : 2) : 0) * 3
            + ((cls & 1) ? (yw < 4 ? 1 : 2) : 0);
    if (rn != rm2) v += 2.0f;
    bmc[idx] = f2b(v * 1.4426950408889634f);
}

// LayerNorm over C=192 -> bf16. mode 0: linear; 1: window gather; 2: shifted gather.
__global__ __launch_bounds__(256) void ln_kernel(
    const float* __restrict__ x, const float* __restrict__ g,
    const float* __restrict__ b, unsigned short* __restrict__ out, int mode, int row_off)
{
    int r = blockIdx.x * 4 + (threadIdx.x >> 6);
    int lane = threadIdx.x & 63;
    int t = (mode == 0) ? (row_off + r) : win_row_to_token(row_off + r, mode == 2);
    const float* xp = x + (size_t)t * 192;
    float v0 = xp[lane], v1 = xp[lane + 64], v2 = xp[lane + 128];
    float s = v0 + v1 + v2;
    float sq = v0 * v0 + v1 * v1 + v2 * v2;
    #pragma unroll
    for (int off = 32; off; off >>= 1) {
        s += __shfl_xor(s, off);
        sq += __shfl_xor(sq, off);
    }
    float mu = s * (1.0f / 192.0f);
    float var = sq * (1.0f / 192.0f) - mu * mu;
    float rs = rsqrtf(var + 1e-5f);
    unsigned short* op = out + (size_t)r * 192;
    op[lane]       = f2b((v0 - mu) * rs * g[lane]       + b[lane]);
    op[lane + 64]  = f2b((v1 - mu) * rs * g[lane + 64]  + b[lane + 64]);
    op[lane + 128] = f2b((v2 - mu) * rs * g[lane + 128] + b[lane + 128]);
}

// bf16 MFMA GEMM (qkv / proj). 128x96 tile, BK=64. (unchanged)
__global__ __launch_bounds__(256) void gemm_kernel(
    const unsigned short* __restrict__ A, const unsigned short* __restrict__ Wb,
    const float* __restrict__ bias, void* outp, const float* resx,
    int N, int K, int ep, int shifted, int row_off)
{
    __shared__ __align__(16) short LDS_[128 * 64 + 96 * 64];   // 28672 B
    short* As = LDS_;
    short* Bs = LDS_ + 128 * 64;
    const int ntiles = N / 96;
    const int NB = gridDim.x;
    int L = blockIdx.x;
    if ((NB & 7) == 0) {
        L = (blockIdx.x & 7) * (NB >> 3) + (blockIdx.x >> 3);
    }
    const int bm = L / ntiles;
    const int bn = L - bm * ntiles;
    const int r0 = bm << 7, n0 = bn * 96;
    const int tid = threadIdx.x;
    const int wid = tid >> 6, lane = tid & 63;
    const int hi = lane >> 4, l15 = lane & 15;
    const int wrow = (wid >> 1) << 6;
    const int wcol = (wid & 1) * 48;
    const int srow = lane >> 3;
    const int sslot = lane & 7;

    f32x4 acc[4][3];
    #pragma unroll
    for (int mi = 0; mi < 4; ++mi)
        #pragma unroll
        for (int ni = 0; ni < 3; ++ni)
            acc[mi][ni] = (f32x4){0.f, 0.f, 0.f, 0.f};

    for (int k0 = 0; k0 < K; k0 += 64) {
        #pragma unroll
        for (int g = 0; g < 4; ++g) {
            int row = wid * 32 + g * 8 + srow;
            const unsigned short* src =
                A + (size_t)(r0 + row) * K + k0 + ((sslot ^ (row & 7)) << 3);
            GLOAD_LDS16(src, &As[(wid * 32 + g * 8) * 64]);
        }
        #pragma unroll
        for (int g = 0; g < 3; ++g) {
            int row = wid * 24 + g * 8 + srow;
            const unsigned short* src =
                Wb + (size_t)(n0 + row) * K + k0 + ((sslot ^ (row & 7)) << 3);
            GLOAD_LDS16(src, &Bs[(wid * 24 + g * 8) * 64]);
        }
        __syncthreads();
        #pragma unroll
        for (int ks = 0; ks < 2; ++ks) {
            const int q = ks * 4 + hi;
            s16x8 bfr[3];
            #pragma unroll
            for (int ni = 0; ni < 3; ++ni) {
                int col = wcol + ni * 16 + l15;
                bfr[ni] = *(const s16x8*)&Bs[col * 64 + ((q ^ (col & 7)) << 3)];
            }
            #pragma unroll
            for (int mi = 0; mi < 4; ++mi) {
                int row = wrow + mi * 16 + l15;
                s16x8 afr = *(const s16x8*)&As[row * 64 + ((q ^ (row & 7)) << 3)];
                #pragma unroll
                for (int ni = 0; ni < 3; ++ni)
                    acc[mi][ni] = __builtin_amdgcn_mfma_f32_16x16x32_bf16(
                        afr, bfr[ni], acc[mi][ni], 0, 0, 0);
            }
        }
        __syncthreads();
    }

    if (ep <= 1) {
        #pragma unroll
        for (int mi = 0; mi < 4; ++mi)
            #pragma unroll
            for (int ni = 0; ni < 3; ++ni) {
                float bv = bias[n0 + wcol + ni * 16 + l15];
                #pragma unroll
                for (int rg = 0; rg < 4; ++rg) {
                    float v = acc[mi][ni][rg] + bv;
                    LDS_[(wrow + mi * 16 + hi * 4 + rg) * 104 + wcol + ni * 16 + l15] =
                        (short)f2b(v);
                }
            }
        __syncthreads();
        #pragma unroll
        for (int it = 0; it < 6; ++it) {
            int idx = tid + it * 256;        // 1536 = 128 rows x 12 chunks
            int row = idx / 12, ch = idx - (idx / 12) * 12;
            s16x8 v = *(const s16x8*)&LDS_[row * 104 + ch * 8];
            *(s16x8*)&((unsigned short*)outp)[(size_t)(r0 + row) * N + n0 + ch * 8] = v;
        }
    } else {
        float* F = (float*)LDS_;
        #pragma unroll
        for (int h = 0; h < 2; ++h) {
            if ((wid >> 1) == h) {
                #pragma unroll
                for (int mi = 0; mi < 4; ++mi)
                    #pragma unroll
                    for (int ni = 0; ni < 3; ++ni) {
                        float bv = bias[n0 + wcol + ni * 16 + l15];
                        #pragma unroll
                        for (int rg = 0; rg < 4; ++rg)
                            F[(mi * 16 + hi * 4 + rg) * 100 + wcol + ni * 16 + l15] =
                                acc[mi][ni][rg] + bv;
                    }
            }
            __syncthreads();
            #pragma unroll
            for (int it = 0; it < 6; ++it) {
                int idx = tid + it * 256;
                int row = idx / 24, ch = idx - (idx / 24) * 24;
                float4 v = *(const float4*)&F[row * 100 + ch * 4];
                int rowl = r0 + h * 64 + row;
                int tt = (ep == 2) ? win_row_to_token(row_off + rowl, shifted) : rowl;
                size_t o = (size_t)tt * 192 + n0 + ch * 4;
                const float4 rx = *(const float4*)&resx[o];
                v.x += rx.x; v.y += rx.y; v.z += rx.z; v.w += rx.w;
                *(float4*)&((float*)outp)[o] = v;
            }
            __syncthreads();
        }
    }
}

// Fused MLP (R15 proven config, verbatim): 64-row blocks, 256 threads (4 waves),
// hc=32, A in registers. LDS = W1c + W2c + Hb = 28.7 KB -> 4 blocks/CU.
__global__ __launch_bounds__(256, 4) void mlp_kernel(
    const unsigned short* __restrict__ Ab,   // [CR][192] ln2-out bf16 (local rows)
    const unsigned short* __restrict__ W1b,  // [768][192]
    const float* __restrict__ b1,            // [768]
    const unsigned short* __restrict__ W2b,  // [192][768]
    const float* __restrict__ b2,            // [192]
    float* out)                              // global f32, pre-offset; in-place +=
{
    __shared__ __align__(16) unsigned short W1c[32 * 192];   // 12288 B
    __shared__ __align__(16) unsigned short W2c[192 * 32];   // 12288 B
    __shared__ __align__(16) unsigned short Hb[64 * 32];     //  4096 B

    const int tid = threadIdx.x;
    const int w = tid >> 6, lane = tid & 63;
    const int hi = lane >> 4, l15 = lane & 15;
    const int r0 = blockIdx.x << 6;
    const int arow = r0 + w * 16 + l15;

    s16x8 afr[6];
    #pragma unroll
    for (int ks = 0; ks < 6; ++ks)
        afr[ks] = *(const s16x8*)&Ab[(size_t)arow * 192 + ks * 32 + hi * 8];

    f32x4 oacc[12];
    #pragma unroll
    for (int ni = 0; ni < 12; ++ni) oacc[ni] = (f32x4){0.f, 0.f, 0.f, 0.f};

    for (int hc = 0; hc < 24; ++hc) {
        #pragma unroll
        for (int it = 0; it < 3; ++it) {
            int sbase = (w * 3 + it) * 64;
            int s = sbase + lane;
            int row = s / 24, c = s - row * 24;
            int cs = (c & 24) | ((c & 7) ^ (row & 7));
            GLOAD_LDS16(&W1b[(size_t)(hc * 32 + row) * 192 + cs * 8], &W1c[sbase * 8]);
        }
        #pragma unroll
        for (int it = 0; it < 3; ++it) {
            int sbase = (w * 3 + it) * 64;
            int s = sbase + lane;
            int row = s >> 2, sp = s & 3;
            int cs = sp ^ (row & 3);
            GLOAD_LDS16(&W2b[(size_t)row * 768 + hc * 32 + cs * 8], &W2c[sbase * 8]);
        }
        __syncthreads();

        f32x4 hacc[2];
        hacc[0] = (f32x4){0.f, 0.f, 0.f, 0.f};
        hacc[1] = (f32x4){0.f, 0.f, 0.f, 0.f};
        #pragma unroll
        for (int ks = 0; ks < 6; ++ks) {
            int slot = ks * 4 + hi;
            #pragma unroll
            for (int nc = 0; nc < 2; ++nc) {
                int col = nc * 16 + l15;
                int cs = (slot & 24) | ((slot & 7) ^ (col & 7));
                s16x8 bfr = *(const s16x8*)&W1c[col * 192 + cs * 8];
                hacc[nc] = __builtin_amdgcn_mfma_f32_16x16x32_bf16(
                    afr[ks], bfr, hacc[nc], 0, 0, 0);
            }
        }
        #pragma unroll
        for (int nc = 0; nc < 2; ++nc) {
            int col = nc * 16 + l15;
            float bv = b1[hc * 32 + col];
            int slot = col >> 3;
            #pragma unroll
            for (int rg = 0; rg < 4; ++rg) {
                float v = hacc[nc][rg] + bv;
                float y = 0.7978845608028654f * fmaf(0.044715f * v, v * v, v);
                y = fminf(fmaxf(y, -15.f), 15.f);
                float z = exp2f(2.8853900817779268f * y);
                v = v * z / (z + 1.0f);
                int row = w * 16 + hi * 4 + rg;
                Hb[row * 32 + ((slot ^ (row & 3)) << 3) + (col & 7)] = f2b(v);
            }
        }
        __syncthreads();

        {
            int cs = (hi ^ (arow & 3)) << 3;
            s16x8 pfr = *(const s16x8*)&Hb[(w * 16 + l15) * 32 + cs];
            #pragma unroll
            for (int ni = 0; ni < 12; ++ni) {
                int w2row = ni * 16 + l15;
                int cs2 = (hi ^ (w2row & 3)) << 3;
                s16x8 bfr2 = *(const s16x8*)&W2c[w2row * 32 + cs2];
                oacc[ni] = __builtin_amdgcn_mfma_f32_16x16x32_bf16(
                    pfr, bfr2, oacc[ni], 0, 0, 0);
            }
        }
        __syncthreads();
    }

    #pragma unroll
    for (int p = 0; p < 4; ++p) {
        if (w == p) {
            #pragma unroll
            for (int ni = 0; ni < 12; ++ni) {
                int col = ni * 16 + l15;
                float bv = b2[col];
                #pragma unroll
                for (int rg = 0; rg < 4; ++rg)
                    ((float*)W1c)[(hi * 4 + rg) * 192 + col] = oacc[ni][rg] + bv;
            }
        }
        __syncthreads();
        #pragma unroll
        for (int it = 0; it < 3; ++it) {
            int idx = tid + it * 256;        // 768 = 16 rows x 48 float4-chunks
            int row = idx / 48, ch = idx - (idx / 48) * 48;
            float4 v = *(const float4*)&((float*)W1c)[row * 192 + ch * 4];
            size_t o = (size_t)(r0 + p * 16 + row) * 192 + ch * 4;
            const float4 rx = *(const float4*)&out[o];
            v.x += rx.x; v.y += rx.y; v.z += rx.z; v.w += rx.w;
            *(float4*)&out[o] = v;
        }
        __syncthreads();
    }
}

// MFMA attention, swapped QK^T. PU shrunk to 98 rows (26.7 KB) so 6 blocks/CU;
// P-writes guarded to q<98; PV prow read clamps to row 97 (garbage rows feed
// only discarded outputs since A-fragment rows are per-lane).
__global__ __launch_bounds__(256, 6) void attn_kernel(
    const unsigned short* __restrict__ qkv, const unsigned short* __restrict__ bmc,
    unsigned short* __restrict__ out, int shifted, int widx_off)
{
    __shared__ __align__(16) short PU[98 * 136];   // Vt[32][136] then P[98][136]

    const int wloc = blockIdx.x;
    const int head = blockIdx.y;
    const int tid = threadIdx.x;
    const int wid = tid >> 6, lane = tid & 63;
    const int hi = lane >> 4, l15 = lane & 15;
    const int r0 = wloc * 98;
    const float scale2 = 0.17677669529663687f * 1.4426950408889634f;

    const int remw = (widx_off + wloc) & 511;
    const int dW = remw >> 6, hW = (remw >> 3) & 7, wW = remw & 7;
    const int cls = shifted ? (((dW == 7) << 2) | ((hW == 7) << 1) | (wW == 7)) : 0;
    const unsigned short* bmch = bmc + ((size_t)cls * 6 + head) * 9604;

    // stage V transposed into PU (rows dd 0..31, cols kv, stride 136)
    for (int idx = tid; idx < 1568; idx += 256) {
        int n = idx >> 4, dp = idx & 15;
        unsigned vv = *(const unsigned*)&qkv[(size_t)(r0 + n) * 576 + 384 + head * 32 + dp * 2];
        ((unsigned short*)PU)[(2 * dp) * 136 + n]     = (unsigned short)(vv & 0xffff);
        ((unsigned short*)PU)[(2 * dp + 1) * 136 + n] = (unsigned short)(vv >> 16);
    }
    for (int idx = tid; idx < 960; idx += 256) {
        int dd = idx / 30, kvp = 98 + (idx - (idx / 30) * 30);
        ((unsigned short*)PU)[dd * 136 + kvp] = 0;
    }
    __syncthreads();

    s16x8 vfr[4][2];
    #pragma unroll
    for (int ks = 0; ks < 4; ++ks) {
        vfr[ks][0] = *(const s16x8*)&PU[(2 * l15) * 136 + ks * 32 + hi * 8];
        vfr[ks][1] = *(const s16x8*)&PU[(2 * l15 + 1) * 136 + ks * 32 + hi * 8];
    }
    s16x8 kfr[7];
    #pragma unroll
    for (int nt = 0; nt < 7; ++nt) {
        int kr = nt * 16 + l15; if (kr > 97) kr = 97;
        kfr[nt] = *(const s16x8*)&qkv[(size_t)(r0 + kr) * 576 + 192 + head * 32 + hi * 8];
    }
    __syncthreads();   // all Vt reads done; PU becomes P

    unsigned short* P = (unsigned short*)PU;
    #pragma unroll
    for (int t = 0; t < 2; ++t) {
        int mt = wid + 4 * t;
        if (mt < 7) {
            int q = mt * 16 + l15;          // this lane's q (swapped layout)
            int qr = q > 97 ? 97 : q;
            s16x8 qa = *(const s16x8*)&qkv[(size_t)(r0 + qr) * 576 + head * 32 + hi * 8];
            f32x4 sacc[7];
            #pragma unroll
            for (int nt = 0; nt < 7; ++nt)
                sacc[nt] = __builtin_amdgcn_mfma_f32_16x16x32_bf16(
                    kfr[nt], qa, (f32x4){0.f, 0.f, 0.f, 0.f}, 0, 0, 0);
            const int kvb = hi * 4;
            #pragma unroll
            for (int nt = 0; nt < 7; ++nt) {
                unsigned bb0 = *(const unsigned*)&bmch[qr * 98 + nt * 16 + kvb];
                unsigned bb1 = *(const unsigned*)&bmch[qr * 98 + nt * 16 + kvb + 2];
                #pragma unroll
                for (int rg = 0; rg < 4; ++rg) {
                    int kv = nt * 16 + kvb + rg;
                    unsigned bu = (rg < 2) ? bb0 : bb1;
                    float bias = b2f((unsigned short)((rg & 1) ? (bu >> 16) : (bu & 0xffffu)));
                    float val = -1e30f;
                    if (q < 98 && kv < 98)
                        val = fmaf(sacc[nt][rg], scale2, bias);
                    sacc[nt][rg] = val;
                }
            }
            float mx = sacc[0][0];
            #pragma unroll
            for (int nt = 0; nt < 7; ++nt)
                #pragma unroll
                for (int rg = 0; rg < 4; ++rg) mx = fmaxf(mx, sacc[nt][rg]);
            mx = fmaxf(mx, __shfl_xor(mx, 16));
            mx = fmaxf(mx, __shfl_xor(mx, 32));
            float sum = 0.f;
            #pragma unroll
            for (int nt = 0; nt < 7; ++nt)
                #pragma unroll
                for (int rg = 0; rg < 4; ++rg) {
                    float e = exp2f(sacc[nt][rg] - mx);
                    sacc[nt][rg] = e;
                    sum += e;
                }
            sum += __shfl_xor(sum, 16);
            sum += __shfl_xor(sum, 32);
            float inv = 1.0f / sum;
            if (q < 98) {                    // rows >= 98 no longer exist in PU
                #pragma unroll
                for (int nt = 0; nt < 7; ++nt) {
                    uint2 wv;
                    wv.x = (unsigned)f2b(sacc[nt][0] * inv) | ((unsigned)f2b(sacc[nt][1] * inv) << 16);
                    wv.y = (unsigned)f2b(sacc[nt][2] * inv) | ((unsigned)f2b(sacc[nt][3] * inv) << 16);
                    *(uint2*)&P[q * 136 + nt * 16 + kvb] = wv;
                }
                if (hi == 0) {
                    const s16x8 z8 = (s16x8){0, 0, 0, 0, 0, 0, 0, 0};
                    *(s16x8*)&P[q * 136 + 112] = z8;
                    *(s16x8*)&P[q * 136 + 120] = z8;
                }
            }
        }
    }
    __syncthreads();

    // PV: prow clamped to row 97 (lanes feeding q>=98 produce discarded output)
    #pragma unroll
    for (int t = 0; t < 2; ++t) {
        int mt = wid + 4 * t;
        if (mt < 7) {
            int pr = mt * 16 + l15; if (pr > 97) pr = 97;
            f32x4 o0 = {0.f, 0.f, 0.f, 0.f}, o1 = {0.f, 0.f, 0.f, 0.f};
            const short* prow = &PU[pr * 136 + hi * 8];
            #pragma unroll
            for (int ks = 0; ks < 4; ++ks) {
                s16x8 pa = *(const s16x8*)&prow[ks * 32];
                o0 = __builtin_amdgcn_mfma_f32_16x16x32_bf16(pa, vfr[ks][0], o0, 0, 0, 0);
                o1 = __builtin_amdgcn_mfma_f32_16x16x32_bf16(pa, vfr[ks][1], o1, 0, 0, 0);
            }
            #pragma unroll
            for (int rg = 0; rg < 4; ++rg) {
                int q = mt * 16 + hi * 4 + rg;
                if (q < 98) {
                    unsigned pv = (unsigned)f2b(o0[rg]) | ((unsigned)f2b(o1[rg]) << 16);
                    *(unsigned*)&out[(size_t)(r0 + q) * 192 + head * 32 + 2 * l15] = pv;
                }
            }
        }
    }
}

extern "C" void kernel_launch(void* const* d_in, const int* in_sizes, int n_in,
                              void* d_out, int out_size, void* d_ws, size_t ws_size,
                              hipStream_t stream) {
    (void)in_sizes; (void)n_in; (void)out_size;
    const float* x      = (const float*)d_in[0];
    const float* ln1_g  = (const float*)d_in[1];
    const float* ln1_b  = (const float*)d_in[2];
    const float* qkv_w  = (const float*)d_in[3];
    const float* qkv_b  = (const float*)d_in[4];
    const float* proj_w = (const float*)d_in[5];
    const float* proj_b = (const float*)d_in[6];
    const float* table  = (const float*)d_in[7];
    const float* ln2_g  = (const float*)d_in[8];
    const float* ln2_b  = (const float*)d_in[9];
    const float* fc1_w  = (const float*)d_in[10];
    const float* fc1_b  = (const float*)d_in[11];
    const float* fc2_w  = (const float*)d_in[12];
    const float* fc2_b  = (const float*)d_in[13];
    float* out = (float*)d_out;

    const int NQ = 576 * 192, NP = 192 * 192, N1 = 768 * 192, N2 = 192 * 768;
    const size_t WTOT = 2ull * (NQ + NP + N1 + N2);
    unsigned short* wq = (unsigned short*)d_ws;
    unsigned short* wp = wq + 2 * NQ;
    unsigned short* w1 = wp + 2 * NP;
    unsigned short* w2 = w1 + 2 * N1;
    unsigned short* bmc = wq + WTOT;
    unsigned short* bufbase = bmc + 921984;
    const size_t fixed_bytes = (WTOT + 921984) * 2;

    const size_t per_win_bytes = 98ull * (192 + 576) * sizeof(unsigned short);
    int wpc = 64;
    const int cands[5] = {1024, 512, 256, 128, 64};
    for (int ci = 0; ci < 5; ++ci) {
        if (fixed_bytes + (size_t)cands[ci] * per_win_bytes <= ws_size) { wpc = cands[ci]; break; }
    }
    const int NC = 1024 / wpc;
    const int CR = 98 * wpc;
    unsigned short* bufA = bufbase;
    unsigned short* bufQ = bufA + (size_t)CR * 192;

    f2b_kernel<<<(2 * NQ + 255) / 256, 256, 0, stream>>>(qkv_w,  wq, 2 * NQ);
    f2b_kernel<<<(2 * NP + 255) / 256, 256, 0, stream>>>(proj_w, wp, 2 * NP);
    f2b_kernel<<<(2 * N1 + 255) / 256, 256, 0, stream>>>(fc1_w,  w1, 2 * N1);
    f2b_kernel<<<(2 * N2 + 255) / 256, 256, 0, stream>>>(fc2_w,  w2, 2 * N2);
    bias_kernel<<<(921984 + 255) / 256, 256, 0, stream>>>(table, bmc);

    for (int i = 0; i < 2; ++i) {
        const int shifted = (i == 1);
        const float* xsrc = (i == 0) ? x : out;
        for (int c = 0; c < NC; ++c) {
            const int row_off = c * CR;
            const int widx_off = c * wpc;
            ln_kernel<<<CR / 4, 256, 0, stream>>>(
                xsrc, ln1_g + i * 192, ln1_b + i * 192, bufA, shifted ? 2 : 1, row_off);
            gemm_kernel<<<(CR / 128) * 6, 256, 0, stream>>>(
                bufA, wq + (size_t)i * NQ, qkv_b + i * 576,
                bufQ, nullptr, 576, 192, 0, 0, 0);
            attn_kernel<<<dim3(wpc, 6), 256, 0, stream>>>(
                bufQ, bmc + (size_t)i * 460992, bufA, shifted, widx_off);
            gemm_kernel<<<(CR / 128) * 2, 256, 0, stream>>>(
                bufA, wp + (size_t)i * NP, proj_b + i * 192,
                out, xsrc, 192, 192, 2, shifted, row_off);
        }
        for (int c = 0; c < NC; ++c) {
            const int row_off = c * CR;
            ln_kernel<<<CR / 4, 256, 0, stream>>>(
                out, ln2_g + i * 192, ln2_b + i * 192, bufA, 0, row_off);
            mlp_kernel<<<CR / 64, 256, 0, stream>>>(
                bufA, w1 + (size_t)i * N1, fc1_b + (size_t)i * 768,
                w2 + (size_t)i * N2, fc2_b + (size_t)i * 192,
                out + (size_t)row_off * 192);
        }
    }
}

// Round 19
// 708.868 us; speedup vs baseline: 1.2863x; 1.2863x over previous
//
#include <hip/hip_runtime.h>
#include <math.h>

#define T_TOKENS 100352

typedef short s16x8 __attribute__((ext_vector_type(8)));
typedef float f32x4 __attribute__((ext_vector_type(4)));

__device__ __forceinline__ unsigned short f2b(float f) {
    union { float f; unsigned u; } x; x.f = f;
    unsigned r = x.u + 0x7fffu + ((x.u >> 16) & 1u);   // RNE
    return (unsigned short)(r >> 16);
}
__device__ __forceinline__ float b2f(unsigned short h) {
    union { unsigned u; float f; } x; x.u = (unsigned)h << 16;
    return x.f;
}

#define GLOAD_LDS16(gsrc, ldst) __builtin_amdgcn_global_load_lds( \
    (const __attribute__((address_space(1))) void*)(gsrc), \
    (__attribute__((address_space(3))) void*)(ldst), 16, 0, 0)

__device__ __forceinline__ int win_row_to_token(int r, int shifted) {
    int widx = r / 98;
    int n = r - widx * 98;
    int b = widx >> 9;
    int remw = widx & 511;
    int dW = remw >> 6, hW = (remw >> 3) & 7, wW = remw & 7;
    int zd = n / 49;
    int nr = n - zd * 49;
    int zh = nr / 7, zw = nr - zh * 7;
    int d = dW * 2 + zd, h = hW * 7 + zh, w = wW * 7 + zw;
    if (shifted) {
        d = (d + 1) & 15;
        h += 3; if (h >= 56) h -= 56;
        w += 3; if (w >= 56) w -= 56;
    }
    return ((b * 16 + d) * 56 + h) * 56 + w;
}

__global__ __launch_bounds__(256) void f2b_kernel(
    const float* __restrict__ in, unsigned short* __restrict__ out, int n)
{
    int i = blockIdx.x * 256 + threadIdx.x;
    if (i < n) out[i] = f2b(in[i]);
}

// Combined bias+mask map, pre-scaled by log2(e), bf16.
__global__ __launch_bounds__(256) void bias_kernel(
    const float* __restrict__ table, unsigned short* __restrict__ bmc)
{
    int idx = blockIdx.x * 256 + threadIdx.x;
    if (idx >= 921984) return;
    int l = idx / 460992;
    int r = idx - l * 460992;
    int cls = r / 57624;
    int r2 = r - cls * 57624;
    int h = r2 / 9604;
    int e = r2 - h * 9604;
    int n = e / 98, m = e - n * 98;
    int zd = n / 49, nr = n - zd * 49, zh = nr / 7, zw = nr - zh * 7;
    int yd = m / 49, mr = m - yd * 49, yh = mr / 7, yw = mr - yh * 7;
    int rpi = (zd - yd + 1) * 169 + (zh - yh + 6) * 13 + (zw - yw + 6);
    float v = table[l * 3042 + rpi * 6 + h];
    int rn = (((cls >> 2) & 1) ? 1 + zd : 0) * 9
           + (((cls >> 1) & 1) ? (zh < 4 ? 1 : 2) : 0) * 3
           + ((cls & 1) ? (zw < 4 ? 1 : 2) : 0);
    int rm2 = (((cls >> 2) & 1) ? 1 + yd : 0) * 9
            + (((cls >> 1) & 1) ? (yh < 4 ? 1 : 2) : 0) * 3
            + ((cls & 1) ? (yw < 4 ? 1 : 2) : 0);
    if (rn != rm2) v += 2.0f;
    bmc[idx] = f2b(v * 1.4426950408889634f);
}

// LayerNorm over C=192 -> bf16 (window-gather modes only now).
__global__ __launch_bounds__(256) void ln_kernel(
    const float* __restrict__ x, const float* __restrict__ g,
    const float* __restrict__ b, unsigned short* __restrict__ out, int mode, int row_off)
{
    int r = blockIdx.x * 4 + (threadIdx.x >> 6);
    int lane = threadIdx.x & 63;
    int t = (mode == 0) ? (row_off + r) : win_row_to_token(row_off + r, mode == 2);
    const float* xp = x + (size_t)t * 192;
    float v0 = xp[lane], v1 = xp[lane + 64], v2 = xp[lane + 128];
    float s = v0 + v1 + v2;
    float sq = v0 * v0 + v1 * v1 + v2 * v2;
    #pragma unroll
    for (int off = 32; off; off >>= 1) {
        s += __shfl_xor(s, off);
        sq += __shfl_xor(sq, off);
    }
    float mu = s * (1.0f / 192.0f);
    float var = sq * (1.0f / 192.0f) - mu * mu;
    float rs = rsqrtf(var + 1e-5f);
    unsigned short* op = out + (size_t)r * 192;
    op[lane]       = f2b((v0 - mu) * rs * g[lane]       + b[lane]);
    op[lane + 64]  = f2b((v1 - mu) * rs * g[lane + 64]  + b[lane + 64]);
    op[lane + 128] = f2b((v2 - mu) * rs * g[lane + 128] + b[lane + 128]);
}

// bf16 MFMA GEMM (qkv / proj). 128x96 tile, BK=64. (unchanged)
__global__ __launch_bounds__(256) void gemm_kernel(
    const unsigned short* __restrict__ A, const unsigned short* __restrict__ Wb,
    const float* __restrict__ bias, void* outp, const float* resx,
    int N, int K, int ep, int shifted, int row_off)
{
    __shared__ __align__(16) short LDS_[128 * 64 + 96 * 64];   // 28672 B
    short* As = LDS_;
    short* Bs = LDS_ + 128 * 64;
    const int ntiles = N / 96;
    const int NB = gridDim.x;
    int L = blockIdx.x;
    if ((NB & 7) == 0) {
        L = (blockIdx.x & 7) * (NB >> 3) + (blockIdx.x >> 3);
    }
    const int bm = L / ntiles;
    const int bn = L - bm * ntiles;
    const int r0 = bm << 7, n0 = bn * 96;
    const int tid = threadIdx.x;
    const int wid = tid >> 6, lane = tid & 63;
    const int hi = lane >> 4, l15 = lane & 15;
    const int wrow = (wid >> 1) << 6;
    const int wcol = (wid & 1) * 48;
    const int srow = lane >> 3;
    const int sslot = lane & 7;

    f32x4 acc[4][3];
    #pragma unroll
    for (int mi = 0; mi < 4; ++mi)
        #pragma unroll
        for (int ni = 0; ni < 3; ++ni)
            acc[mi][ni] = (f32x4){0.f, 0.f, 0.f, 0.f};

    for (int k0 = 0; k0 < K; k0 += 64) {
        #pragma unroll
        for (int g = 0; g < 4; ++g) {
            int row = wid * 32 + g * 8 + srow;
            const unsigned short* src =
                A + (size_t)(r0 + row) * K + k0 + ((sslot ^ (row & 7)) << 3);
            GLOAD_LDS16(src, &As[(wid * 32 + g * 8) * 64]);
        }
        #pragma unroll
        for (int g = 0; g < 3; ++g) {
            int row = wid * 24 + g * 8 + srow;
            const unsigned short* src =
                Wb + (size_t)(n0 + row) * K + k0 + ((sslot ^ (row & 7)) << 3);
            GLOAD_LDS16(src, &Bs[(wid * 24 + g * 8) * 64]);
        }
        __syncthreads();
        #pragma unroll
        for (int ks = 0; ks < 2; ++ks) {
            const int q = ks * 4 + hi;
            s16x8 bfr[3];
            #pragma unroll
            for (int ni = 0; ni < 3; ++ni) {
                int col = wcol + ni * 16 + l15;
                bfr[ni] = *(const s16x8*)&Bs[col * 64 + ((q ^ (col & 7)) << 3)];
            }
            #pragma unroll
            for (int mi = 0; mi < 4; ++mi) {
                int row = wrow + mi * 16 + l15;
                s16x8 afr = *(const s16x8*)&As[row * 64 + ((q ^ (row & 7)) << 3)];
                #pragma unroll
                for (int ni = 0; ni < 3; ++ni)
                    acc[mi][ni] = __builtin_amdgcn_mfma_f32_16x16x32_bf16(
                        afr, bfr[ni], acc[mi][ni], 0, 0, 0);
            }
        }
        __syncthreads();
    }

    if (ep <= 1) {
        #pragma unroll
        for (int mi = 0; mi < 4; ++mi)
            #pragma unroll
            for (int ni = 0; ni < 3; ++ni) {
                float bv = bias[n0 + wcol + ni * 16 + l15];
                #pragma unroll
                for (int rg = 0; rg < 4; ++rg) {
                    float v = acc[mi][ni][rg] + bv;
                    LDS_[(wrow + mi * 16 + hi * 4 + rg) * 104 + wcol + ni * 16 + l15] =
                        (short)f2b(v);
                }
            }
        __syncthreads();
        #pragma unroll
        for (int it = 0; it < 6; ++it) {
            int idx = tid + it * 256;        // 1536 = 128 rows x 12 chunks
            int row = idx / 12, ch = idx - (idx / 12) * 12;
            s16x8 v = *(const s16x8*)&LDS_[row * 104 + ch * 8];
            *(s16x8*)&((unsigned short*)outp)[(size_t)(r0 + row) * N + n0 + ch * 8] = v;
        }
    } else {
        float* F = (float*)LDS_;
        #pragma unroll
        for (int h = 0; h < 2; ++h) {
            if ((wid >> 1) == h) {
                #pragma unroll
                for (int mi = 0; mi < 4; ++mi)
                    #pragma unroll
                    for (int ni = 0; ni < 3; ++ni) {
                        float bv = bias[n0 + wcol + ni * 16 + l15];
                        #pragma unroll
                        for (int rg = 0; rg < 4; ++rg)
                            F[(mi * 16 + hi * 4 + rg) * 100 + wcol + ni * 16 + l15] =
                                acc[mi][ni][rg] + bv;
                    }
            }
            __syncthreads();
            #pragma unroll
            for (int it = 0; it < 6; ++it) {
                int idx = tid + it * 256;
                int row = idx / 24, ch = idx - (idx / 24) * 24;
                float4 v = *(const float4*)&F[row * 100 + ch * 4];
                int rowl = r0 + h * 64 + row;
                int tt = (ep == 2) ? win_row_to_token(row_off + rowl, shifted) : rowl;
                size_t o = (size_t)tt * 192 + n0 + ch * 4;
                const float4 rx = *(const float4*)&resx[o];
                v.x += rx.x; v.y += rx.y; v.z += rx.z; v.w += rx.w;
                *(float4*)&((float*)outp)[o] = v;
            }
            __syncthreads();
        }
    }
}

// Fused LN2 + MLP (R15 schedule): x += GELU(LN(x)@W1^T+b1)@W2^T+b2.
// 64-row blocks, 256 threads (4 waves), hc=32, A in registers via 2-pass LN
// (4 hi-lanes share a row; 2-shuffle reduce; reread is L1-hot).
// LDS = W1c + W2c + Hb = 28.7 KB -> 4 blocks/CU.
__global__ __launch_bounds__(256, 4) void mlp_kernel(
    float* xio,                              // [T][192] f32 (LN input + residual io)
    const float* __restrict__ lg, const float* __restrict__ lb,
    const unsigned short* __restrict__ W1b,  // [768][192]
    const float* __restrict__ b1,            // [768]
    const unsigned short* __restrict__ W2b,  // [192][768]
    const float* __restrict__ b2)            // [192]
{
    __shared__ __align__(16) unsigned short W1c[32 * 192];   // 12288 B
    __shared__ __align__(16) unsigned short W2c[192 * 32];   // 12288 B
    __shared__ __align__(16) unsigned short Hb[64 * 32];     //  4096 B

    const int tid = threadIdx.x;
    const int w = tid >> 6, lane = tid & 63;
    const int hi = lane >> 4, l15 = lane & 15;
    const int r0 = blockIdx.x << 6;
    const int arow = r0 + w * 16 + l15;

    // ---- fused LN2, two-pass (stats, then normalize -> bf16 fragments) ----
    const float* xp = xio + (size_t)arow * 192;
    float s = 0.f, sq = 0.f;
    #pragma unroll
    for (int ks = 0; ks < 6; ++ks) {
        float4 a = *(const float4*)&xp[ks * 32 + hi * 8];
        float4 c = *(const float4*)&xp[ks * 32 + hi * 8 + 4];
        s += a.x + a.y + a.z + a.w + c.x + c.y + c.z + c.w;
        sq = fmaf(a.x, a.x, sq); sq = fmaf(a.y, a.y, sq);
        sq = fmaf(a.z, a.z, sq); sq = fmaf(a.w, a.w, sq);
        sq = fmaf(c.x, c.x, sq); sq = fmaf(c.y, c.y, sq);
        sq = fmaf(c.z, c.z, sq); sq = fmaf(c.w, c.w, sq);
    }
    s += __shfl_xor(s, 16);  sq += __shfl_xor(sq, 16);
    s += __shfl_xor(s, 32);  sq += __shfl_xor(sq, 32);
    const float mu = s * (1.0f / 192.0f);
    const float rs = rsqrtf(sq * (1.0f / 192.0f) - mu * mu + 1e-5f);

    s16x8 afr[6];
    #pragma unroll
    for (int ks = 0; ks < 6; ++ks) {
        float4 a = *(const float4*)&xp[ks * 32 + hi * 8];
        float4 c = *(const float4*)&xp[ks * 32 + hi * 8 + 4];
        float4 g0 = *(const float4*)&lg[ks * 32 + hi * 8];
        float4 g1 = *(const float4*)&lg[ks * 32 + hi * 8 + 4];
        float4 b0 = *(const float4*)&lb[ks * 32 + hi * 8];
        float4 b1v = *(const float4*)&lb[ks * 32 + hi * 8 + 4];
        afr[ks][0] = (short)f2b((a.x - mu) * rs * g0.x + b0.x);
        afr[ks][1] = (short)f2b((a.y - mu) * rs * g0.y + b0.y);
        afr[ks][2] = (short)f2b((a.z - mu) * rs * g0.z + b0.z);
        afr[ks][3] = (short)f2b((a.w - mu) * rs * g0.w + b0.w);
        afr[ks][4] = (short)f2b((c.x - mu) * rs * g1.x + b1v.x);
        afr[ks][5] = (short)f2b((c.y - mu) * rs * g1.y + b1v.y);
        afr[ks][6] = (short)f2b((c.z - mu) * rs * g1.z + b1v.z);
        afr[ks][7] = (short)f2b((c.w - mu) * rs * g1.w + b1v.w);
    }

    f32x4 oacc[12];
    #pragma unroll
    for (int ni = 0; ni < 12; ++ni) oacc[ni] = (f32x4){0.f, 0.f, 0.f, 0.f};

    for (int hc = 0; hc < 24; ++hc) {
        #pragma unroll
        for (int it = 0; it < 3; ++it) {
            int sbase = (w * 3 + it) * 64;
            int s2 = sbase + lane;
            int row = s2 / 24, c = s2 - row * 24;
            int cs = (c & 24) | ((c & 7) ^ (row & 7));
            GLOAD_LDS16(&W1b[(size_t)(hc * 32 + row) * 192 + cs * 8], &W1c[sbase * 8]);
        }
        #pragma unroll
        for (int it = 0; it < 3; ++it) {
            int sbase = (w * 3 + it) * 64;
            int s2 = sbase + lane;
            int row = s2 >> 2, sp = s2 & 3;
            int cs = sp ^ (row & 3);
            GLOAD_LDS16(&W2b[(size_t)row * 768 + hc * 32 + cs * 8], &W2c[sbase * 8]);
        }
        __syncthreads();

        f32x4 hacc[2];
        hacc[0] = (f32x4){0.f, 0.f, 0.f, 0.f};
        hacc[1] = (f32x4){0.f, 0.f, 0.f, 0.f};
        #pragma unroll
        for (int ks = 0; ks < 6; ++ks) {
            int slot = ks * 4 + hi;
            #pragma unroll
            for (int nc = 0; nc < 2; ++nc) {
                int col = nc * 16 + l15;
                int cs = (slot & 24) | ((slot & 7) ^ (col & 7));
                s16x8 bfr = *(const s16x8*)&W1c[col * 192 + cs * 8];
                hacc[nc] = __builtin_amdgcn_mfma_f32_16x16x32_bf16(
                    afr[ks], bfr, hacc[nc], 0, 0, 0);
            }
        }
        #pragma unroll
        for (int nc = 0; nc < 2; ++nc) {
            int col = nc * 16 + l15;
            float bv = b1[hc * 32 + col];
            int slot = col >> 3;
            #pragma unroll
            for (int rg = 0; rg < 4; ++rg) {
                float v = hacc[nc][rg] + bv;
                float y = 0.7978845608028654f * fmaf(0.044715f * v, v * v, v);
                y = fminf(fmaxf(y, -15.f), 15.f);
                float z = exp2f(2.8853900817779268f * y);
                v = v * z / (z + 1.0f);
                int row = w * 16 + hi * 4 + rg;
                Hb[row * 32 + ((slot ^ (row & 3)) << 3) + (col & 7)] = f2b(v);
            }
        }
        __syncthreads();

        {
            int cs = (hi ^ (arow & 3)) << 3;
            s16x8 pfr = *(const s16x8*)&Hb[(w * 16 + l15) * 32 + cs];
            #pragma unroll
            for (int ni = 0; ni < 12; ++ni) {
                int w2row = ni * 16 + l15;
                int cs2 = (hi ^ (w2row & 3)) << 3;
                s16x8 bfr2 = *(const s16x8*)&W2c[w2row * 32 + cs2];
                oacc[ni] = __builtin_amdgcn_mfma_f32_16x16x32_bf16(
                    pfr, bfr2, oacc[ni], 0, 0, 0);
            }
        }
        __syncthreads();
    }

    // epilogue: 4 passes of 16 rows staged as f32 [16][192] in W1c (12288 B)
    #pragma unroll
    for (int p = 0; p < 4; ++p) {
        if (w == p) {
            #pragma unroll
            for (int ni = 0; ni < 12; ++ni) {
                int col = ni * 16 + l15;
                float bv = b2[col];
                #pragma unroll
                for (int rg = 0; rg < 4; ++rg)
                    ((float*)W1c)[(hi * 4 + rg) * 192 + col] = oacc[ni][rg] + bv;
            }
        }
        __syncthreads();
        #pragma unroll
        for (int it = 0; it < 3; ++it) {
            int idx = tid + it * 256;        // 768 = 16 rows x 48 float4-chunks
            int row = idx / 48, ch = idx - (idx / 48) * 48;
            float4 v = *(const float4*)&((float*)W1c)[row * 192 + ch * 4];
            size_t o = (size_t)(r0 + p * 16 + row) * 192 + ch * 4;
            const float4 rx = *(const float4*)&xio[o];
            v.x += rx.x; v.y += rx.y; v.z += rx.z; v.w += rx.w;
            *(float4*)&xio[o] = v;
        }
        __syncthreads();
    }
}

// MFMA attention, swapped QK^T (R12/R15 proven version).
__global__ __launch_bounds__(256, 4) void attn_kernel(
    const unsigned short* __restrict__ qkv, const unsigned short* __restrict__ bmc,
    unsigned short* __restrict__ out, int shifted, int widx_off)
{
    __shared__ __align__(16) short PU[112 * 136];   // Vt[32][136] then P[112][136]

    const int wloc = blockIdx.x;
    const int head = blockIdx.y;
    const int tid = threadIdx.x;
    const int wid = tid >> 6, lane = tid & 63;
    const int hi = lane >> 4, l15 = lane & 15;
    const int r0 = wloc * 98;
    const float scale2 = 0.17677669529663687f * 1.4426950408889634f;

    const int remw = (widx_off + wloc) & 511;
    const int dW = remw >> 6, hW = (remw >> 3) & 7, wW = remw & 7;
    const int cls = shifted ? (((dW == 7) << 2) | ((hW == 7) << 1) | (wW == 7)) : 0;
    const unsigned short* bmch = bmc + ((size_t)cls * 6 + head) * 9604;

    for (int idx = tid; idx < 1568; idx += 256) {
        int n = idx >> 4, dp = idx & 15;
        unsigned vv = *(const unsigned*)&qkv[(size_t)(r0 + n) * 576 + 384 + head * 32 + dp * 2];
        ((unsigned short*)PU)[(2 * dp) * 136 + n]     = (unsigned short)(vv & 0xffff);
        ((unsigned short*)PU)[(2 * dp + 1) * 136 + n] = (unsigned short)(vv >> 16);
    }
    for (int idx = tid; idx < 960; idx += 256) {
        int dd = idx / 30, kvp = 98 + (idx - (idx / 30) * 30);
        ((unsigned short*)PU)[dd * 136 + kvp] = 0;
    }
    __syncthreads();

    s16x8 vfr[4][2];
    #pragma unroll
    for (int ks = 0; ks < 4; ++ks) {
        vfr[ks][0] = *(const s16x8*)&PU[(2 * l15) * 136 + ks * 32 + hi * 8];
        vfr[ks][1] = *(const s16x8*)&PU[(2 * l15 + 1) * 136 + ks * 32 + hi * 8];
    }
    s16x8 kfr[7];
    #pragma unroll
    for (int nt = 0; nt < 7; ++nt) {
        int kr = nt * 16 + l15; if (kr > 97) kr = 97;
        kfr[nt] = *(const s16x8*)&qkv[(size_t)(r0 + kr) * 576 + 192 + head * 32 + hi * 8];
    }
    __syncthreads();   // all Vt reads done; PU becomes P

    unsigned short* P = (unsigned short*)PU;
    #pragma unroll
    for (int t = 0; t < 2; ++t) {
        int mt = wid + 4 * t;
        if (mt < 7) {
            int q = mt * 16 + l15;
            int qr = q > 97 ? 97 : q;
            s16x8 qa = *(const s16x8*)&qkv[(size_t)(r0 + qr) * 576 + head * 32 + hi * 8];
            f32x4 sacc[7];
            #pragma unroll
            for (int nt = 0; nt < 7; ++nt)
                sacc[nt] = __builtin_amdgcn_mfma_f32_16x16x32_bf16(
                    kfr[nt], qa, (f32x4){0.f, 0.f, 0.f, 0.f}, 0, 0, 0);
            const int kvb = hi * 4;
            #pragma unroll
            for (int nt = 0; nt < 7; ++nt) {
                unsigned bb0 = *(const unsigned*)&bmch[qr * 98 + nt * 16 + kvb];
                unsigned bb1 = *(const unsigned*)&bmch[qr * 98 + nt * 16 + kvb + 2];
                #pragma unroll
                for (int rg = 0; rg < 4; ++rg) {
                    int kv = nt * 16 + kvb + rg;
                    unsigned bu = (rg < 2) ? bb0 : bb1;
                    float bias = b2f((unsigned short)((rg & 1) ? (bu >> 16) : (bu & 0xffffu)));
                    float val = -1e30f;
                    if (q < 98 && kv < 98)
                        val = fmaf(sacc[nt][rg], scale2, bias);
                    sacc[nt][rg] = val;
                }
            }
            float mx = sacc[0][0];
            #pragma unroll
            for (int nt = 0; nt < 7; ++nt)
                #pragma unroll
                for (int rg = 0; rg < 4; ++rg) mx = fmaxf(mx, sacc[nt][rg]);
            mx = fmaxf(mx, __shfl_xor(mx, 16));
            mx = fmaxf(mx, __shfl_xor(mx, 32));
            float sum = 0.f;
            #pragma unroll
            for (int nt = 0; nt < 7; ++nt)
                #pragma unroll
                for (int rg = 0; rg < 4; ++rg) {
                    float e = exp2f(sacc[nt][rg] - mx);
                    sacc[nt][rg] = e;
                    sum += e;
                }
            sum += __shfl_xor(sum, 16);
            sum += __shfl_xor(sum, 32);
            float inv = 1.0f / sum;
            #pragma unroll
            for (int nt = 0; nt < 7; ++nt) {
                uint2 wv;
                wv.x = (unsigned)f2b(sacc[nt][0] * inv) | ((unsigned)f2b(sacc[nt][1] * inv) << 16);
                wv.y = (unsigned)f2b(sacc[nt][2] * inv) | ((unsigned)f2b(sacc[nt][3] * inv) << 16);
                *(uint2*)&P[q * 136 + nt * 16 + kvb] = wv;
            }
            if (hi == 0) {
                const s16x8 z8 = (s16x8){0, 0, 0, 0, 0, 0, 0, 0};
                *(s16x8*)&P[q * 136 + 112] = z8;
                *(s16x8*)&P[q * 136 + 120] = z8;
            }
        }
    }
    __syncthreads();

    #pragma unroll
    for (int t = 0; t < 2; ++t) {
        int mt = wid + 4 * t;
        if (mt < 7) {
            f32x4 o0 = {0.f, 0.f, 0.f, 0.f}, o1 = {0.f, 0.f, 0.f, 0.f};
            const short* prow = &PU[(mt * 16 + l15) * 136 + hi * 8];
            #pragma unroll
            for (int ks = 0; ks < 4; ++ks) {
                s16x8 pa = *(const s16x8*)&prow[ks * 32];
                o0 = __builtin_amdgcn_mfma_f32_16x16x32_bf16(pa, vfr[ks][0], o0, 0, 0, 0);
                o1 = __builtin_amdgcn_mfma_f32_16x16x32_bf16(pa, vfr[ks][1], o1, 0, 0, 0);
            }
            #pragma unroll
            for (int rg = 0; rg < 4; ++rg) {
                int q = mt * 16 + hi * 4 + rg;
                if (q < 98) {
                    unsigned pv = (unsigned)f2b(o0[rg]) | ((unsigned)f2b(o1[rg]) << 16);
                    *(unsigned*)&out[(size_t)(r0 + q) * 192 + head * 32 + 2 * l15] = pv;
                }
            }
        }
    }
}

extern "C" void kernel_launch(void* const* d_in, const int* in_sizes, int n_in,
                              void* d_out, int out_size, void* d_ws, size_t ws_size,
                              hipStream_t stream) {
    (void)in_sizes; (void)n_in; (void)out_size;
    const float* x      = (const float*)d_in[0];
    const float* ln1_g  = (const float*)d_in[1];
    const float* ln1_b  = (const float*)d_in[2];
    const float* qkv_w  = (const float*)d_in[3];
    const float* qkv_b  = (const float*)d_in[4];
    const float* proj_w = (const float*)d_in[5];
    const float* proj_b = (const float*)d_in[6];
    const float* table  = (const float*)d_in[7];
    const float* ln2_g  = (const float*)d_in[8];
    const float* ln2_b  = (const float*)d_in[9];
    const float* fc1_w  = (const float*)d_in[10];
    const float* fc1_b  = (const float*)d_in[11];
    const float* fc2_w  = (const float*)d_in[12];
    const float* fc2_b  = (const float*)d_in[13];
    float* out = (float*)d_out;

    const int NQ = 576 * 192, NP = 192 * 192, N1 = 768 * 192, N2 = 192 * 768;
    const size_t WTOT = 2ull * (NQ + NP + N1 + N2);
    unsigned short* wq = (unsigned short*)d_ws;
    unsigned short* wp = wq + 2 * NQ;
    unsigned short* w1 = wp + 2 * NP;
    unsigned short* w2 = w1 + 2 * N1;
    unsigned short* bmc = wq + WTOT;
    unsigned short* bufbase = bmc + 921984;
    const size_t fixed_bytes = (WTOT + 921984) * 2;

    const size_t per_win_bytes = 98ull * (192 + 576) * sizeof(unsigned short);
    int wpc = 64;
    const int cands[5] = {1024, 512, 256, 128, 64};
    for (int ci = 0; ci < 5; ++ci) {
        if (fixed_bytes + (size_t)cands[ci] * per_win_bytes <= ws_size) { wpc = cands[ci]; break; }
    }
    const int NC = 1024 / wpc;
    const int CR = 98 * wpc;
    unsigned short* bufA = bufbase;
    unsigned short* bufQ = bufA + (size_t)CR * 192;

    f2b_kernel<<<(2 * NQ + 255) / 256, 256, 0, stream>>>(qkv_w,  wq, 2 * NQ);
    f2b_kernel<<<(2 * NP + 255) / 256, 256, 0, stream>>>(proj_w, wp, 2 * NP);
    f2b_kernel<<<(2 * N1 + 255) / 256, 256, 0, stream>>>(fc1_w,  w1, 2 * N1);
    f2b_kernel<<<(2 * N2 + 255) / 256, 256, 0, stream>>>(fc2_w,  w2, 2 * N2);
    bias_kernel<<<(921984 + 255) / 256, 256, 0, stream>>>(table, bmc);

    for (int i = 0; i < 2; ++i) {
        const int shifted = (i == 1);
        const float* xsrc = (i == 0) ? x : out;
        for (int c = 0; c < NC; ++c) {
            const int row_off = c * CR;
            const int widx_off = c * wpc;
            ln_kernel<<<CR / 4, 256, 0, stream>>>(
                xsrc, ln1_g + i * 192, ln1_b + i * 192, bufA, shifted ? 2 : 1, row_off);
            gemm_kernel<<<(CR / 128) * 6, 256, 0, stream>>>(
                bufA, wq + (size_t)i * NQ, qkv_b + i * 576,
                bufQ, nullptr, 576, 192, 0, 0, 0);
            attn_kernel<<<dim3(wpc, 6), 256, 0, stream>>>(
                bufQ, bmc + (size_t)i * 460992, bufA, shifted, widx_off);
            gemm_kernel<<<(CR / 128) * 2, 256, 0, stream>>>(
                bufA, wp + (size_t)i * NP, proj_b + i * 192,
                out, xsrc, 192, 192, 2, shifted, row_off);
        }
        // fused LN2+MLP over all tokens, one dispatch per layer
        mlp_kernel<<<T_TOKENS / 64, 256, 0, stream>>>(
            out, ln2_g + i * 192, ln2_b + i * 192,
            w1 + (size_t)i * N1, fc1_b + (size_t)i * 768,
            w2 + (size_t)i * N2, fc2_b + (size_t)i * 192);
    }
}